// Round 11
// baseline (1127.000 us; speedup 1.0000x reference)
//
#include <hip/hip_runtime.h>
#include <hip/hip_fp16.h>
#include <hip/hip_cooperative_groups.h>

namespace cg = cooperative_groups;

typedef __attribute__((ext_vector_type(8))) _Float16 half8;
typedef __attribute__((ext_vector_type(4))) float f32x4;

static __device__ __forceinline__ half8 as_half8(uint4 u) {
    union { uint4 u; half8 h; } c; c.u = u; return c.h;
}

__device__ __forceinline__ void acc4(float* a, uint2 v, float w) {
    __half2 h0 = *(__half2*)&v.x;
    __half2 h1 = *(__half2*)&v.y;
    float2 f0 = __half22float2(h0);
    float2 f1 = __half22float2(h1);
    a[0] = fmaf(f0.x, w, a[0]);
    a[1] = fmaf(f0.y, w, a[1]);
    a[2] = fmaf(f1.x, w, a[2]);
    a[3] = fmaf(f1.y, w, a[3]);
}

// One cooperative kernel: all setup phases + 4 GCN layers, grid.sync() between.
__global__ __launch_bounds__(256, 4) void mega_k(
        const float* __restrict__ x, const int* __restrict__ srcI, const int* __restrict__ dstI,
        const float* __restrict__ W0, const float* __restrict__ W1,
        const float* __restrict__ W2, const float* __restrict__ W3,
        const float* __restrict__ b0, const float* __restrict__ b1,
        const float* __restrict__ b2, const float* __restrict__ b3,
        float* outF,
        int* cnt, int* rowptr, float* dinv, int* bsum,
        int* rank, int* pos, unsigned int* payload, unsigned int* edata,
        uint4* Wshuf, __half* Xh, __half* Hh,
        int N, int E, int S) {
    cg::grid_group grid = cg::this_grid();
    const int tid = threadIdx.x;
    const int gtid = blockIdx.x * 256 + tid;
    const int gsz = gridDim.x * 256;
    const int nE4 = E >> 2;
    __shared__ int wsh[4];

    // ---- phase 0: zero cnt + W pre-shuffle (fp32 -> fp16 MFMA fragment order) ----
    for (int i = gtid; i < 12544; i += gsz) ((int4*)cnt)[i] = make_int4(0, 0, 0, 0);
    for (int gid = gtid; gid < 8192; gid += gsz) {
        int layer = gid >> 11;
        int t2 = gid & 2047;
        int ks = t2 >> 9;
        int rem = t2 & 511;
        int ct = rem >> 6;
        int lane = rem & 63;
        const float* W = (layer == 0) ? W0 : (layer == 1) ? W1 : (layer == 2) ? W2 : W3;
        int col = ct * 16 + (lane & 15);
        int k0 = ks * 32 + (lane >> 4) * 8;
        __half h[8];
#pragma unroll
        for (int j = 0; j < 8; ++j) h[j] = __float2half(W[(k0 + j) * 128 + col]);
        uint4 o;
        o.x = *(unsigned int*)&h[0];
        o.y = *(unsigned int*)&h[2];
        o.z = *(unsigned int*)&h[4];
        o.w = *(unsigned int*)&h[6];
        Wshuf[gid] = o;
    }
    grid.sync();

    // ---- phase 1: histogram + per-edge rank ----
    for (int e4 = gtid; e4 <= nE4; e4 += gsz) {
        if (e4 < nE4) {
            int4 d = ((const int4*)dstI)[e4];
            int4 r;
            r.x = atomicAdd(&cnt[d.x], 1);
            r.y = atomicAdd(&cnt[d.y], 1);
            r.z = atomicAdd(&cnt[d.z], 1);
            r.w = atomicAdd(&cnt[d.w], 1);
            ((int4*)rank)[e4] = r;
        } else {
            for (int e = nE4 * 4; e < E; ++e) rank[e] = atomicAdd(&cnt[dstI[e]], 1);
        }
    }
    grid.sync();

    // ---- phase 2: per-chunk sums + dinv ----
    int nChunks = (N + 1023) >> 10;
    for (int b = blockIdx.x; b < nChunks; b += gridDim.x) {
        int base = b * 1024 + tid * 4;
        int4 v = make_int4(0, 0, 0, 0);
        if (base + 3 < N) v = *(const int4*)(cnt + base);
        else {
            if (base + 0 < N) v.x = cnt[base + 0];
            if (base + 1 < N) v.y = cnt[base + 1];
            if (base + 2 < N) v.z = cnt[base + 2];
        }
        if (base + 3 < N) {
            float4 dv;
            dv.x = rsqrtf((float)v.x + 1.0f);
            dv.y = rsqrtf((float)v.y + 1.0f);
            dv.z = rsqrtf((float)v.z + 1.0f);
            dv.w = rsqrtf((float)v.w + 1.0f);
            *(float4*)(dinv + base) = dv;
        } else {
            if (base + 0 < N) dinv[base + 0] = rsqrtf((float)v.x + 1.0f);
            if (base + 1 < N) dinv[base + 1] = rsqrtf((float)v.y + 1.0f);
            if (base + 2 < N) dinv[base + 2] = rsqrtf((float)v.z + 1.0f);
        }
        int s = v.x + v.y + v.z + v.w;
#pragma unroll
        for (int off = 32; off; off >>= 1) s += __shfl_xor(s, off, 64);
        if ((tid & 63) == 0) wsh[tid >> 6] = s;
        __syncthreads();
        if (tid == 0) bsum[b] = wsh[0] + wsh[1] + wsh[2] + wsh[3];
        __syncthreads();
    }
    grid.sync();

    // ---- phase 3: exclusive scan -> rowptr ----
    for (int b = blockIdx.x; b < nChunks; b += gridDim.x) {
        int lane = tid & 63, wid = tid >> 6;
        int base = b * 1024 + tid * 4;
        int4 v = make_int4(0, 0, 0, 0);
        if (base + 3 < N) v = *(const int4*)(cnt + base);
        else {
            if (base + 0 < N) v.x = cnt[base + 0];
            if (base + 1 < N) v.y = cnt[base + 1];
            if (base + 2 < N) v.z = cnt[base + 2];
        }
        int s = v.x + v.y + v.z + v.w;
        int incl = s;
#pragma unroll
        for (int off = 1; off < 64; off <<= 1) {
            int t2 = __shfl_up(incl, off, 64);
            if (lane >= off) incl += t2;
        }
        if (lane == 63) wsh[wid] = incl;
        __syncthreads();
        int woff = 0;
        for (int w = 0; w < b; ++w) woff += bsum[w];
        for (int w = 0; w < wid; ++w) woff += wsh[w];
        int e0 = woff + incl - s;
        int o0 = e0 + v.x, o1 = o0 + v.y, o2 = o1 + v.z, o3 = o2 + v.w;
        if (base + 0 < N) rowptr[base + 1] = o0;
        if (base + 1 < N) rowptr[base + 2] = o1;
        if (base + 2 < N) rowptr[base + 3] = o2;
        if (base + 3 < N) rowptr[base + 4] = o3;
        if (b == 0 && tid == 0) rowptr[0] = 0;
        __syncthreads();
    }
    grid.sync();

    // ---- phase 4a: pos + payload ----
    for (int e4 = gtid; e4 <= nE4; e4 += gsz) {
        if (e4 < nE4) {
            int4 d = ((const int4*)dstI)[e4];
            int4 s = ((const int4*)srcI)[e4];
            int4 r = ((const int4*)rank)[e4];
            int ds[4] = {d.x, d.y, d.z, d.w};
            int ss[4] = {s.x, s.y, s.z, s.w};
            int rs[4] = {r.x, r.y, r.z, r.w};
            int4 po;
            uint4 py;
            int* pop = &po.x;
            unsigned int* pyp = &py.x;
#pragma unroll
            for (int j = 0; j < 4; ++j) {
                pop[j] = rowptr[ds[j]] + rs[j];
                float w = dinv[ss[j]] * dinv[ds[j]];
                unsigned short wh = __half_as_ushort(__float2half(w));
                pyp[j] = ((unsigned int)ss[j] << 16) | (unsigned int)wh;
            }
            ((int4*)pos)[e4] = po;
            ((uint4*)payload)[e4] = py;
        } else {
            for (int e = nE4 * 4; e < E; ++e) {
                int d = dstI[e], s = srcI[e];
                pos[e] = rowptr[d] + rank[e];
                float w = dinv[s] * dinv[d];
                unsigned short wh = __half_as_ushort(__float2half(w));
                payload[e] = ((unsigned int)s << 16) | (unsigned int)wh;
            }
        }
    }
    grid.sync();

    // ---- phase 4b: XCD-striped scatter into edata ----
    int gE4 = (nE4 + 1 + 255) >> 8;
    int nVB = gE4 * 8;
    for (int vb = blockIdx.x; vb < nVB; vb += gridDim.x) {
        int stripe = vb & 7;
        int lo = stripe * S;
        int hi = min(E, lo + S);
        int e4 = (vb >> 3) * 256 + tid;
        if (e4 < nE4) {
            int4 p = ((const int4*)pos)[e4];
            uint4 y = ((const uint4*)payload)[e4];
            if (p.x >= lo && p.x < hi) edata[p.x] = y.x;
            if (p.y >= lo && p.y < hi) edata[p.y] = y.y;
            if (p.z >= lo && p.z < hi) edata[p.z] = y.z;
            if (p.w >= lo && p.w < hi) edata[p.w] = y.w;
        } else if (e4 == nE4) {
            for (int e = nE4 * 4; e < E; ++e) {
                int p = pos[e];
                if (p >= lo && p < hi) edata[p] = payload[e];
            }
        }
    }
    grid.sync();

    // ---- 4 layers: gemm (MFMA, swapped operands) -> gather ----
    int nRB = (N + 63) >> 6;       // 64-node row-blocks (16 nodes/wave)
    int G = (N * 16 + 255) >> 8;   // gather groups
    for (int l = 0; l < 4; ++l) {
        const uint4* Wsh = Wshuf + l * 2048;
        // -- gemm: H = X @ W_l, fp16 out; W-fragments read from global (L2-hot) --
        for (int vb = blockIdx.x; vb < nRB; vb += gridDim.x) {
            int lane = tid & 63;
            int wv = tid >> 6;
            int rbase = vb * 64 + wv * 16;
            int lr = lane & 15;
            int lk = lane >> 4;
            f32x4 acc[8];
#pragma unroll
            for (int ct = 0; ct < 8; ++ct) acc[ct] = (f32x4){0.f, 0.f, 0.f, 0.f};
#pragma unroll
            for (int ks = 0; ks < 4; ++ks) {
                half8 a;
                int row = rbase + lr;
                if (l == 0) {
                    half8 h = (half8)(_Float16)0;
                    if (row < N) {
                        const float4* xf = (const float4*)(x + (size_t)row * 128 + (ks * 4 + lk) * 8);
                        float4 f0 = xf[0];
                        float4 f1 = xf[1];
                        h[0] = (_Float16)f0.x; h[1] = (_Float16)f0.y;
                        h[2] = (_Float16)f0.z; h[3] = (_Float16)f0.w;
                        h[4] = (_Float16)f1.x; h[5] = (_Float16)f1.y;
                        h[6] = (_Float16)f1.z; h[7] = (_Float16)f1.w;
                    }
                    a = h;
                } else {
                    uint4 u = (row < N) ? ((const uint4*)Xh)[(size_t)row * 16 + ks * 4 + lk]
                                        : make_uint4(0, 0, 0, 0);
                    a = as_half8(u);
                }
#pragma unroll
                for (int ct = 0; ct < 8; ++ct) {
                    half8 bfr = as_half8(Wsh[(ks * 8 + ct) * 64 + lane]);
                    // swapped: D = W^T · X^T (node in D-col, 4 consecutive H-cols in D-rows)
                    acc[ct] = __builtin_amdgcn_mfma_f32_16x16x32_f16(bfr, a, acc[ct], 0, 0, 0);
                }
            }
            int node = rbase + lr;
            if (node < N) {
#pragma unroll
                for (int ct = 0; ct < 8; ++ct) {
                    f32x4 v = acc[ct];
                    __half2 h0 = __floats2half2_rn(v[0], v[1]);
                    __half2 h1 = __floats2half2_rn(v[2], v[3]);
                    uint2 o;
                    o.x = *(unsigned int*)&h0;
                    o.y = *(unsigned int*)&h1;
                    *(uint2*)(Hh + (size_t)node * 128 + ct * 16 + lk * 4) = o;
                }
            }
        }
        grid.sync();

        // -- gather: out[i] = relu(b + dinv^2*H[i] + sum w_e*H[src]) --
        const float* bias = (l == 0) ? b0 : (l == 1) ? b1 : (l == 2) ? b2 : b3;
        for (int vb = blockIdx.x; vb < 2 * G; vb += gridDim.x) {
            int c = vb & 1;
            int g = vb >> 1;
            int t = g * 256 + tid;
            int i = t >> 4;
            if (i >= N) continue;
            int lane = t & 15;
            int fo = c * 16 + lane;
            const uint2* H2 = (const uint2*)Hh;
            float dn = dinv[i];
            float sn = dn * dn;
            float a[4] = {};
            acc4(a, H2[(size_t)i * 32 + fo], sn);
            int p0 = rowptr[i];
            int p1 = rowptr[i + 1];
            int p = p0;
            for (; p + 8 <= p1; p += 8) {
                unsigned int e0 = edata[p + 0];
                unsigned int e1 = edata[p + 1];
                unsigned int e2 = edata[p + 2];
                unsigned int e3 = edata[p + 3];
                unsigned int e4 = edata[p + 4];
                unsigned int e5 = edata[p + 5];
                unsigned int e6 = edata[p + 6];
                unsigned int e7 = edata[p + 7];
                uint2 v0 = H2[(size_t)(e0 >> 16) * 32 + fo];
                uint2 v1 = H2[(size_t)(e1 >> 16) * 32 + fo];
                uint2 v2 = H2[(size_t)(e2 >> 16) * 32 + fo];
                uint2 v3 = H2[(size_t)(e3 >> 16) * 32 + fo];
                uint2 v4 = H2[(size_t)(e4 >> 16) * 32 + fo];
                uint2 v5 = H2[(size_t)(e5 >> 16) * 32 + fo];
                uint2 v6 = H2[(size_t)(e6 >> 16) * 32 + fo];
                uint2 v7 = H2[(size_t)(e7 >> 16) * 32 + fo];
                acc4(a, v0, __half2float(__ushort_as_half((unsigned short)(e0 & 0xffffu))));
                acc4(a, v1, __half2float(__ushort_as_half((unsigned short)(e1 & 0xffffu))));
                acc4(a, v2, __half2float(__ushort_as_half((unsigned short)(e2 & 0xffffu))));
                acc4(a, v3, __half2float(__ushort_as_half((unsigned short)(e3 & 0xffffu))));
                acc4(a, v4, __half2float(__ushort_as_half((unsigned short)(e4 & 0xffffu))));
                acc4(a, v5, __half2float(__ushort_as_half((unsigned short)(e5 & 0xffffu))));
                acc4(a, v6, __half2float(__ushort_as_half((unsigned short)(e6 & 0xffffu))));
                acc4(a, v7, __half2float(__ushort_as_half((unsigned short)(e7 & 0xffffu))));
            }
            for (; p + 4 <= p1; p += 4) {
                unsigned int e0 = edata[p + 0];
                unsigned int e1 = edata[p + 1];
                unsigned int e2 = edata[p + 2];
                unsigned int e3 = edata[p + 3];
                uint2 v0 = H2[(size_t)(e0 >> 16) * 32 + fo];
                uint2 v1 = H2[(size_t)(e1 >> 16) * 32 + fo];
                uint2 v2 = H2[(size_t)(e2 >> 16) * 32 + fo];
                uint2 v3 = H2[(size_t)(e3 >> 16) * 32 + fo];
                acc4(a, v0, __half2float(__ushort_as_half((unsigned short)(e0 & 0xffffu))));
                acc4(a, v1, __half2float(__ushort_as_half((unsigned short)(e1 & 0xffffu))));
                acc4(a, v2, __half2float(__ushort_as_half((unsigned short)(e2 & 0xffffu))));
                acc4(a, v3, __half2float(__ushort_as_half((unsigned short)(e3 & 0xffffu))));
            }
            for (; p < p1; ++p) {
                unsigned int e = edata[p];
                uint2 v = H2[(size_t)(e >> 16) * 32 + fo];
                acc4(a, v, __half2float(__ushort_as_half((unsigned short)(e & 0xffffu))));
            }
            float4 bb = ((const float4*)bias)[fo];
            float r0 = fmaxf(a[0] + bb.x, 0.f);
            float r1 = fmaxf(a[1] + bb.y, 0.f);
            float r2 = fmaxf(a[2] + bb.z, 0.f);
            float r3 = fmaxf(a[3] + bb.w, 0.f);
            if (l < 3) {
                __half2 h0 = __floats2half2_rn(r0, r1);
                __half2 h1 = __floats2half2_rn(r2, r3);
                uint2 o;
                o.x = *(unsigned int*)&h0;
                o.y = *(unsigned int*)&h1;
                ((uint2*)Xh)[(size_t)i * 32 + fo] = o;
            } else {
                *(float4*)(outF + (size_t)i * 128 + fo * 4) = make_float4(r0, r1, r2, r3);
            }
        }
        if (l < 3) grid.sync();
    }
}

// ---------------- launch ----------------

extern "C" void kernel_launch(void* const* d_in, const int* in_sizes, int n_in,
                              void* d_out, int out_size, void* d_ws, size_t ws_size,
                              hipStream_t stream) {
    const float* x = (const float*)d_in[0];
    const int* ei = (const int*)d_in[1];
    int E = in_sizes[1] / 2;
    const int* srcI = ei;
    const int* dstI = ei + E;
    const float* W0 = (const float*)d_in[2];
    const float* b0 = (const float*)d_in[3];
    const float* W1 = (const float*)d_in[4];
    const float* b1 = (const float*)d_in[5];
    const float* W2 = (const float*)d_in[6];
    const float* b2 = (const float*)d_in[7];
    const float* W3 = (const float*)d_in[8];
    const float* b3 = (const float*)d_in[9];
    int N = in_sizes[0] / 128;
    int Ea = (E + 3) & ~3;

    // ws layout (4B units)
    int* iws = (int*)d_ws;
    int* cnt = iws;                              // [0, 50176)
    int* rowptr = iws + 50176;                   // [50176, 100352)
    float* dinv = (float*)(iws + 100352);        // [100352, 150528)
    int* bsum = iws + 150528;                    // 64
    int* rank = iws + 150656;                    // Ea
    int* pos = rank + Ea;                        // Ea
    unsigned int* payload = (unsigned int*)(pos + Ea);   // Ea
    unsigned int* edata = payload + Ea;          // Ea
    uint4* Wshuf = (uint4*)(edata + Ea);         // 8192 uint4
    int* wsEnd = (int*)(Wshuf + 8192);
    __half* Xh = (__half*)wsEnd;                 // N*128 halves
    __half* Hh = (__half*)(wsEnd + (size_t)N * 64);
    float* outF = (float*)d_out;
    int S = (((E + 7) / 8) + 31) & ~31;

    int nb = 0;
    hipOccupancyMaxActiveBlocksPerMultiprocessor(&nb, mega_k, 256, 0);
    if (nb <= 0) nb = 2;
    int dev = 0;
    hipGetDevice(&dev);
    int ncu = 0;
    hipDeviceGetAttribute(&ncu, hipDeviceAttributeMultiprocessorCount, dev);
    if (ncu <= 0) ncu = 256;
    long long gridLL = (long long)nb * ncu;
    int grid = (int)((gridLL > 2048) ? 2048 : gridLL);

    void* args[] = {
        (void*)&x, (void*)&srcI, (void*)&dstI,
        (void*)&W0, (void*)&W1, (void*)&W2, (void*)&W3,
        (void*)&b0, (void*)&b1, (void*)&b2, (void*)&b3,
        (void*)&outF,
        (void*)&cnt, (void*)&rowptr, (void*)&dinv, (void*)&bsum,
        (void*)&rank, (void*)&pos, (void*)&payload, (void*)&edata,
        (void*)&Wshuf, (void*)&Xh, (void*)&Hh,
        (void*)&N, (void*)&E, (void*)&S};
    hipLaunchCooperativeKernel((void*)mega_k, dim3(grid), dim3(256), args, 0, stream);
}

// Round 12
// 262.122 us; speedup vs baseline: 4.2995x; 4.2995x over previous
//
#include <hip/hip_runtime.h>
#include <hip/hip_fp16.h>

typedef __attribute__((ext_vector_type(8))) _Float16 half8;
typedef __attribute__((ext_vector_type(4))) float f32x4;

static __device__ __forceinline__ half8 as_half8(uint4 u) {
    union { uint4 u; half8 h; } c; c.u = u; return c.h;
}

// ---------------- setup kernels (once per call) ----------------

// rank[e] = arrival index among edges with same dst (also builds histogram)
__global__ void hist_rank_k(const int* __restrict__ dst, int* __restrict__ cnt,
                            int* __restrict__ rank, int E) {
    int e4 = blockIdx.x * 256 + threadIdx.x;
    int nE4 = E >> 2;
    if (e4 < nE4) {
        int4 d = ((const int4*)dst)[e4];
        int4 r;
        r.x = atomicAdd(&cnt[d.x], 1);
        r.y = atomicAdd(&cnt[d.y], 1);
        r.z = atomicAdd(&cnt[d.z], 1);
        r.w = atomicAdd(&cnt[d.w], 1);
        ((int4*)rank)[e4] = r;
    } else if (e4 == nE4) {
        for (int e = nE4 * 4; e < E; ++e) rank[e] = atomicAdd(&cnt[dst[e]], 1);
    }
}

// per-block sums of cnt (1024/block) + fused dinv = rsqrt(cnt+1)
__global__ void bsum_k(const int* __restrict__ cnt, int* __restrict__ bsum,
                       float* __restrict__ dinv, int n) {
    int b = blockIdx.x, tid = threadIdx.x;
    int base = b * 1024 + tid * 4;
    int4 v = make_int4(0, 0, 0, 0);
    if (base + 3 < n) v = *(const int4*)(cnt + base);
    else {
        if (base + 0 < n) v.x = cnt[base + 0];
        if (base + 1 < n) v.y = cnt[base + 1];
        if (base + 2 < n) v.z = cnt[base + 2];
    }
    if (base + 3 < n) {
        float4 dv;
        dv.x = rsqrtf((float)v.x + 1.0f);
        dv.y = rsqrtf((float)v.y + 1.0f);
        dv.z = rsqrtf((float)v.z + 1.0f);
        dv.w = rsqrtf((float)v.w + 1.0f);
        *(float4*)(dinv + base) = dv;
    } else {
        if (base + 0 < n) dinv[base + 0] = rsqrtf((float)v.x + 1.0f);
        if (base + 1 < n) dinv[base + 1] = rsqrtf((float)v.y + 1.0f);
        if (base + 2 < n) dinv[base + 2] = rsqrtf((float)v.z + 1.0f);
    }
    int s = v.x + v.y + v.z + v.w;
#pragma unroll
    for (int off = 32; off; off >>= 1) s += __shfl_xor(s, off, 64);
    __shared__ int wsh[4];
    if ((tid & 63) == 0) wsh[tid >> 6] = s;
    __syncthreads();
    if (tid == 0) bsum[b] = wsh[0] + wsh[1] + wsh[2] + wsh[3];
}

// exclusive scan -> rowptr; block offset computed by summing bsum[0..b) (<=49 entries)
__global__ void rowscan_k(const int* __restrict__ cnt, const int* __restrict__ bsum,
                          int* __restrict__ rowptr, int n) {
    int b = blockIdx.x, tid = threadIdx.x;
    int lane = tid & 63, wid = tid >> 6;
    int base = b * 1024 + tid * 4;
    int4 v = make_int4(0, 0, 0, 0);
    if (base + 3 < n) v = *(const int4*)(cnt + base);
    else {
        if (base + 0 < n) v.x = cnt[base + 0];
        if (base + 1 < n) v.y = cnt[base + 1];
        if (base + 2 < n) v.z = cnt[base + 2];
    }
    int s = v.x + v.y + v.z + v.w;
    int incl = s;
#pragma unroll
    for (int off = 1; off < 64; off <<= 1) {
        int t = __shfl_up(incl, off, 64);
        if (lane >= off) incl += t;
    }
    __shared__ int wsh[4];
    if (lane == 63) wsh[wid] = incl;
    __syncthreads();
    int woff = 0;
    for (int w = 0; w < b; ++w) woff += bsum[w];  // uniform scalar loop, L2-hot
    for (int w = 0; w < wid; ++w) woff += wsh[w];
    int e0 = woff + incl - s;
    int o0 = e0 + v.x, o1 = o0 + v.y, o2 = o1 + v.z, o3 = o2 + v.w;
    if (base + 0 < n) rowptr[base + 1] = o0;
    if (base + 1 < n) rowptr[base + 2] = o1;
    if (base + 2 < n) rowptr[base + 3] = o2;
    if (base + 3 < n) rowptr[base + 4] = o3;
    if (b == 0 && tid == 0) rowptr[0] = 0;
}

// Fused pospay+scatter: block vb = (chunk, stripe). Each block recomputes
// pos/payload for its edge chunk (L2-hot lookups) and writes only positions
// inside its XCD-pinned stripe. Writes are idempotent across blocks.
__global__ void scatter8_k(const int* __restrict__ src, const int* __restrict__ dst,
                           const int* __restrict__ rank, const int* __restrict__ rowptr,
                           const float* __restrict__ dinv,
                           unsigned int* __restrict__ edata, int E, int S) {
    int stripe = blockIdx.x & 7;
    int lo = stripe * S;
    int hi = min(E, lo + S);
    int e4 = (blockIdx.x >> 3) * 256 + threadIdx.x;
    int nE4 = E >> 2;
    if (e4 < nE4) {
        int4 d = ((const int4*)dst)[e4];
        int4 s = ((const int4*)src)[e4];
        int4 r = ((const int4*)rank)[e4];
        int ds[4] = {d.x, d.y, d.z, d.w};
        int ss[4] = {s.x, s.y, s.z, s.w};
        int rs[4] = {r.x, r.y, r.z, r.w};
#pragma unroll
        for (int j = 0; j < 4; ++j) {
            int p = rowptr[ds[j]] + rs[j];
            if (p >= lo && p < hi) {
                float w = dinv[ss[j]] * dinv[ds[j]];
                unsigned short wh = __half_as_ushort(__float2half(w));
                edata[p] = ((unsigned int)ss[j] << 16) | (unsigned int)wh;
            }
        }
    } else if (e4 == nE4) {
        for (int e = nE4 * 4; e < E; ++e) {
            int p = rowptr[dst[e]] + rank[e];
            if (p >= lo && p < hi) {
                float w = dinv[src[e]] * dinv[dst[e]];
                unsigned short wh = __half_as_ushort(__float2half(w));
                edata[p] = ((unsigned int)src[e] << 16) | (unsigned int)wh;
            }
        }
    }
}

// Pre-shuffle all 4 W matrices into MFMA fragment order (fp16) + zero cnt.
__global__ void wshuf_k(const float* __restrict__ W0, const float* __restrict__ W1,
                        const float* __restrict__ W2, const float* __restrict__ W3,
                        uint4* __restrict__ Wshuf, int* __restrict__ cnt) {
    int gid = blockIdx.x * 256 + threadIdx.x;  // [0, 8192)
    // zero cnt: 12544 int4 over 8192 threads
    for (int i = gid; i < 12544; i += 8192) ((int4*)cnt)[i] = make_int4(0, 0, 0, 0);
    int layer = gid >> 11;
    int tid2 = gid & 2047;
    int ks = tid2 >> 9;
    int rem = tid2 & 511;
    int ct = rem >> 6;
    int lane = rem & 63;
    const float* W = (layer == 0) ? W0 : (layer == 1) ? W1 : (layer == 2) ? W2 : W3;
    int col = ct * 16 + (lane & 15);
    int k0 = ks * 32 + (lane >> 4) * 8;
    __half h[8];
#pragma unroll
    for (int j = 0; j < 8; ++j) h[j] = __float2half(W[(k0 + j) * 128 + col]);
    uint4 o;
    o.x = *(unsigned int*)&h[0];
    o.y = *(unsigned int*)&h[2];
    o.z = *(unsigned int*)&h[4];
    o.w = *(unsigned int*)&h[6];
    Wshuf[gid] = o;
}

// ---------------- per-layer kernels ----------------

// H = X @ W via v_mfma_f32_16x16x32_f16 with SWAPPED operands:
// D = mfma(A=w_frag, B=x_frag) = W^T · X^T -> node in D-col, 4 consecutive
// H-cols in D-rows -> uint2 packed store. 4 waves; block = 256 nodes.
template <bool F32IN>
__global__ __launch_bounds__(256) void gemm_k(const void* __restrict__ Xin,
                                              const uint4* __restrict__ Wsh,
                                              __half* __restrict__ Hh, int N) {
    __shared__ uint4 bsh[2048];  // 32 KB
    int tid = threadIdx.x;
#pragma unroll
    for (int i = 0; i < 8; ++i) bsh[i * 256 + tid] = Wsh[i * 256 + tid];
    __syncthreads();

    int lane = tid & 63;
    int wv = tid >> 6;
    int rbase = blockIdx.x * 256 + wv * 64;
    int lr = lane & 15;
    int lk = lane >> 4;

    f32x4 acc[4][8];
#pragma unroll
    for (int rt = 0; rt < 4; ++rt)
#pragma unroll
        for (int ct = 0; ct < 8; ++ct) acc[rt][ct] = (f32x4){0.f, 0.f, 0.f, 0.f};

#pragma unroll
    for (int ks = 0; ks < 4; ++ks) {
        half8 a[4];
#pragma unroll
        for (int rt = 0; rt < 4; ++rt) {
            int row = rbase + rt * 16 + lr;
            if (F32IN) {
                half8 h = (half8)(_Float16)0;
                if (row < N) {
                    const float4* xf = (const float4*)((const float*)Xin +
                                        (size_t)row * 128 + (ks * 4 + lk) * 8);
                    float4 f0 = xf[0];
                    float4 f1 = xf[1];
                    h[0] = (_Float16)f0.x; h[1] = (_Float16)f0.y;
                    h[2] = (_Float16)f0.z; h[3] = (_Float16)f0.w;
                    h[4] = (_Float16)f1.x; h[5] = (_Float16)f1.y;
                    h[6] = (_Float16)f1.z; h[7] = (_Float16)f1.w;
                }
                a[rt] = h;
            } else {
                uint4 u = (row < N) ? ((const uint4*)Xin)[(size_t)row * 16 + ks * 4 + lk]
                                    : make_uint4(0, 0, 0, 0);
                a[rt] = as_half8(u);
            }
        }
#pragma unroll
        for (int ct = 0; ct < 8; ++ct) {
            half8 b = as_half8(bsh[(ks * 8 + ct) * 64 + lane]);
#pragma unroll
            for (int rt = 0; rt < 4; ++rt) {
                acc[rt][ct] = __builtin_amdgcn_mfma_f32_16x16x32_f16(b, a[rt], acc[rt][ct], 0, 0, 0);
            }
        }
    }

#pragma unroll
    for (int rt = 0; rt < 4; ++rt) {
        int node = rbase + rt * 16 + lr;
        if (node < N) {
#pragma unroll
            for (int ct = 0; ct < 8; ++ct) {
                f32x4 v = acc[rt][ct];
                __half2 h0 = __floats2half2_rn(v[0], v[1]);
                __half2 h1 = __floats2half2_rn(v[2], v[3]);
                uint2 o;
                o.x = *(unsigned int*)&h0;
                o.y = *(unsigned int*)&h1;
                *(uint2*)(Hh + (size_t)node * 128 + ct * 16 + lk * 4) = o;
            }
        }
    }
}

__device__ __forceinline__ void acc4(float* a, uint2 v, float w) {
    __half2 h0 = *(__half2*)&v.x;
    __half2 h1 = *(__half2*)&v.y;
    float2 f0 = __half22float2(h0);
    float2 f1 = __half22float2(h1);
    a[0] = fmaf(f0.x, w, a[0]);
    a[1] = fmaf(f0.y, w, a[1]);
    a[2] = fmaf(f1.x, w, a[2]);
    a[3] = fmaf(f1.y, w, a[3]);
}

// out[i] = relu(b + dinv[i]^2 * H[i] + sum_{e: dst=i} w_e * H[src_e])
// XCD-pinned feature chunks (bid&1 -> 128B half-row); 16 lanes/node x uint2.
template <bool F16OUT>
__global__ __launch_bounds__(256) void gather_agg_k(
        const __half* __restrict__ Hh, const int* __restrict__ rowptr,
        const unsigned int* __restrict__ edata, const float* __restrict__ dinv,
        const float* __restrict__ b, void* __restrict__ out, int N) {
    int bid = blockIdx.x;
    int c = bid & 1;
    int g = bid >> 1;
    int t = g * 256 + threadIdx.x;
    int i = t >> 4;
    if (i >= N) return;
    int lane = t & 15;
    int fo = c * 16 + lane;              // uint2 index within 32-uint2 row
    const uint2* H2 = (const uint2*)Hh;

    float dn = dinv[i];
    float sn = dn * dn;

    float a[4] = {};
    acc4(a, H2[(size_t)i * 32 + fo], sn);

    int p0 = rowptr[i];
    int p1 = rowptr[i + 1];
    int p = p0;
    for (; p + 8 <= p1; p += 8) {
        unsigned int e0 = edata[p + 0];
        unsigned int e1 = edata[p + 1];
        unsigned int e2 = edata[p + 2];
        unsigned int e3 = edata[p + 3];
        unsigned int e4 = edata[p + 4];
        unsigned int e5 = edata[p + 5];
        unsigned int e6 = edata[p + 6];
        unsigned int e7 = edata[p + 7];
        uint2 v0 = H2[(size_t)(e0 >> 16) * 32 + fo];
        uint2 v1 = H2[(size_t)(e1 >> 16) * 32 + fo];
        uint2 v2 = H2[(size_t)(e2 >> 16) * 32 + fo];
        uint2 v3 = H2[(size_t)(e3 >> 16) * 32 + fo];
        uint2 v4 = H2[(size_t)(e4 >> 16) * 32 + fo];
        uint2 v5 = H2[(size_t)(e5 >> 16) * 32 + fo];
        uint2 v6 = H2[(size_t)(e6 >> 16) * 32 + fo];
        uint2 v7 = H2[(size_t)(e7 >> 16) * 32 + fo];
        acc4(a, v0, __half2float(__ushort_as_half((unsigned short)(e0 & 0xffffu))));
        acc4(a, v1, __half2float(__ushort_as_half((unsigned short)(e1 & 0xffffu))));
        acc4(a, v2, __half2float(__ushort_as_half((unsigned short)(e2 & 0xffffu))));
        acc4(a, v3, __half2float(__ushort_as_half((unsigned short)(e3 & 0xffffu))));
        acc4(a, v4, __half2float(__ushort_as_half((unsigned short)(e4 & 0xffffu))));
        acc4(a, v5, __half2float(__ushort_as_half((unsigned short)(e5 & 0xffffu))));
        acc4(a, v6, __half2float(__ushort_as_half((unsigned short)(e6 & 0xffffu))));
        acc4(a, v7, __half2float(__ushort_as_half((unsigned short)(e7 & 0xffffu))));
    }
    for (; p + 4 <= p1; p += 4) {
        unsigned int e0 = edata[p + 0];
        unsigned int e1 = edata[p + 1];
        unsigned int e2 = edata[p + 2];
        unsigned int e3 = edata[p + 3];
        uint2 v0 = H2[(size_t)(e0 >> 16) * 32 + fo];
        uint2 v1 = H2[(size_t)(e1 >> 16) * 32 + fo];
        uint2 v2 = H2[(size_t)(e2 >> 16) * 32 + fo];
        uint2 v3 = H2[(size_t)(e3 >> 16) * 32 + fo];
        acc4(a, v0, __half2float(__ushort_as_half((unsigned short)(e0 & 0xffffu))));
        acc4(a, v1, __half2float(__ushort_as_half((unsigned short)(e1 & 0xffffu))));
        acc4(a, v2, __half2float(__ushort_as_half((unsigned short)(e2 & 0xffffu))));
        acc4(a, v3, __half2float(__ushort_as_half((unsigned short)(e3 & 0xffffu))));
    }
    for (; p < p1; ++p) {
        unsigned int e = edata[p];
        uint2 v = H2[(size_t)(e >> 16) * 32 + fo];
        acc4(a, v, __half2float(__ushort_as_half((unsigned short)(e & 0xffffu))));
    }

    float4 bb = ((const float4*)b)[fo];
    float r0 = fmaxf(a[0] + bb.x, 0.f);
    float r1 = fmaxf(a[1] + bb.y, 0.f);
    float r2 = fmaxf(a[2] + bb.z, 0.f);
    float r3 = fmaxf(a[3] + bb.w, 0.f);

    if (F16OUT) {
        __half2 h0 = __floats2half2_rn(r0, r1);
        __half2 h1 = __floats2half2_rn(r2, r3);
        uint2 o;
        o.x = *(unsigned int*)&h0;
        o.y = *(unsigned int*)&h1;
        ((uint2*)out)[(size_t)i * 32 + fo] = o;
    } else {
        *(float4*)((float*)out + (size_t)i * 128 + fo * 4) = make_float4(r0, r1, r2, r3);
    }
}

// ---------------- launch ----------------

extern "C" void kernel_launch(void* const* d_in, const int* in_sizes, int n_in,
                              void* d_out, int out_size, void* d_ws, size_t ws_size,
                              hipStream_t stream) {
    const float* x = (const float*)d_in[0];
    const int* ei = (const int*)d_in[1];
    const int E = in_sizes[1] / 2;
    const int* srcI = ei;
    const int* dstI = ei + E;
    const float* b[4] = {(const float*)d_in[3], (const float*)d_in[5],
                         (const float*)d_in[7], (const float*)d_in[9]};
    const int N = in_sizes[0] / 128;
    const int Ea = (E + 3) & ~3;

    // ws layout (4B units)
    int* iws = (int*)d_ws;
    int* cnt = iws;                              // [0, 50176)
    int* rowptr = iws + 50176;                   // [50176, 100352)
    float* dinv = (float*)(iws + 100352);        // [100352, 150528)
    int* bsum = iws + 150528;                    // 64
    int* rank = iws + 150656;                    // Ea
    unsigned int* edata = (unsigned int*)(rank + Ea);       // Ea
    uint4* Wshuf = (uint4*)(edata + Ea);         // 8192 uint4
    int* wsEnd = (int*)(Wshuf + 8192);
    __half* Xh = (__half*)wsEnd;                 // N*128 halves (inter-layer act)
    __half* Hh = (__half*)(wsEnd + (size_t)N * 64);

    dim3 blk(256);
    int gE4 = ((E >> 2) + 1 + 255) / 256;
    int NB = (N + 1023) / 1024;
    int gGemm = (N + 255) / 256;
    int G = (N * 16 + 255) / 256;                // node-group count for gather
    int S = (((E + 7) / 8) + 31) & ~31;          // stripe size, 128B-aligned

    wshuf_k<<<32, blk, 0, stream>>>((const float*)d_in[2], (const float*)d_in[4],
                                    (const float*)d_in[6], (const float*)d_in[8], Wshuf, cnt);
    hist_rank_k<<<gE4, blk, 0, stream>>>(dstI, cnt, rank, E);
    bsum_k<<<NB, blk, 0, stream>>>(cnt, bsum, dinv, N);
    rowscan_k<<<NB, blk, 0, stream>>>(cnt, bsum, rowptr, N);
    scatter8_k<<<gE4 * 8, blk, 0, stream>>>(srcI, dstI, rank, rowptr, dinv, edata, E, S);

    for (int l = 0; l < 4; ++l) {
        if (l == 0) gemm_k<true><<<gGemm, blk, 0, stream>>>(x, Wshuf, Hh, N);
        else        gemm_k<false><<<gGemm, blk, 0, stream>>>(Xh, Wshuf + l * 2048, Hh, N);
        if (l == 3) {
            gather_agg_k<false><<<2 * G, blk, 0, stream>>>(Hh, rowptr, edata, dinv, b[l], d_out, N);
        } else {
            gather_agg_k<true><<<2 * G, blk, 0, stream>>>(Hh, rowptr, edata, dinv, b[l], Xh, N);
        }
    }
}

// Round 13
// 251.645 us; speedup vs baseline: 4.4785x; 1.0416x over previous
//
#include <hip/hip_runtime.h>
#include <hip/hip_fp16.h>

typedef __attribute__((ext_vector_type(8))) _Float16 half8;
typedef __attribute__((ext_vector_type(4))) float f32x4;

static __device__ __forceinline__ half8 as_half8(uint4 u) {
    union { uint4 u; half8 h; } c; c.u = u; return c.h;
}

// ---------------- setup kernels (once per call) ----------------

// zero cnt (50176 ints = 12544 int4)
__global__ void zero_k(int* __restrict__ cnt) {
    int i = blockIdx.x * 256 + threadIdx.x;
    if (i < 12544) ((int4*)cnt)[i] = make_int4(0, 0, 0, 0);
}

// rank[e] = arrival index among edges with same dst (also builds histogram)
__global__ void hist_rank_k(const int* __restrict__ dst, int* __restrict__ cnt,
                            int* __restrict__ rank, int E) {
    int e4 = blockIdx.x * 256 + threadIdx.x;
    int nE4 = E >> 2;
    if (e4 < nE4) {
        int4 d = ((const int4*)dst)[e4];
        int4 r;
        r.x = atomicAdd(&cnt[d.x], 1);
        r.y = atomicAdd(&cnt[d.y], 1);
        r.z = atomicAdd(&cnt[d.z], 1);
        r.w = atomicAdd(&cnt[d.w], 1);
        ((int4*)rank)[e4] = r;
    } else if (e4 == nE4) {
        for (int e = nE4 * 4; e < E; ++e) rank[e] = atomicAdd(&cnt[dst[e]], 1);
    }
}

// per-block sums of cnt (1024/block) + fused dinv = rsqrt(cnt+1)
__global__ void bsum_k(const int* __restrict__ cnt, int* __restrict__ bsum,
                       float* __restrict__ dinv, int n) {
    int b = blockIdx.x, tid = threadIdx.x;
    int base = b * 1024 + tid * 4;
    int4 v = make_int4(0, 0, 0, 0);
    if (base + 3 < n) v = *(const int4*)(cnt + base);
    else {
        if (base + 0 < n) v.x = cnt[base + 0];
        if (base + 1 < n) v.y = cnt[base + 1];
        if (base + 2 < n) v.z = cnt[base + 2];
    }
    if (base + 3 < n) {
        float4 dv;
        dv.x = rsqrtf((float)v.x + 1.0f);
        dv.y = rsqrtf((float)v.y + 1.0f);
        dv.z = rsqrtf((float)v.z + 1.0f);
        dv.w = rsqrtf((float)v.w + 1.0f);
        *(float4*)(dinv + base) = dv;
    } else {
        if (base + 0 < n) dinv[base + 0] = rsqrtf((float)v.x + 1.0f);
        if (base + 1 < n) dinv[base + 1] = rsqrtf((float)v.y + 1.0f);
        if (base + 2 < n) dinv[base + 2] = rsqrtf((float)v.z + 1.0f);
    }
    int s = v.x + v.y + v.z + v.w;
#pragma unroll
    for (int off = 32; off; off >>= 1) s += __shfl_xor(s, off, 64);
    __shared__ int wsh[4];
    if ((tid & 63) == 0) wsh[tid >> 6] = s;
    __syncthreads();
    if (tid == 0) bsum[b] = wsh[0] + wsh[1] + wsh[2] + wsh[3];
}

// exclusive scan -> rowptr; block offset computed by summing bsum[0..b) (<=49 entries)
__global__ void rowscan_k(const int* __restrict__ cnt, const int* __restrict__ bsum,
                          int* __restrict__ rowptr, int n) {
    int b = blockIdx.x, tid = threadIdx.x;
    int lane = tid & 63, wid = tid >> 6;
    int base = b * 1024 + tid * 4;
    int4 v = make_int4(0, 0, 0, 0);
    if (base + 3 < n) v = *(const int4*)(cnt + base);
    else {
        if (base + 0 < n) v.x = cnt[base + 0];
        if (base + 1 < n) v.y = cnt[base + 1];
        if (base + 2 < n) v.z = cnt[base + 2];
    }
    int s = v.x + v.y + v.z + v.w;
    int incl = s;
#pragma unroll
    for (int off = 1; off < 64; off <<= 1) {
        int t = __shfl_up(incl, off, 64);
        if (lane >= off) incl += t;
    }
    __shared__ int wsh[4];
    if (lane == 63) wsh[wid] = incl;
    __syncthreads();
    int woff = 0;
    for (int w = 0; w < b; ++w) woff += bsum[w];  // uniform scalar loop, L2-hot
    for (int w = 0; w < wid; ++w) woff += wsh[w];
    int e0 = woff + incl - s;
    int o0 = e0 + v.x, o1 = o0 + v.y, o2 = o1 + v.z, o3 = o2 + v.w;
    if (base + 0 < n) rowptr[base + 1] = o0;
    if (base + 1 < n) rowptr[base + 2] = o1;
    if (base + 2 < n) rowptr[base + 3] = o2;
    if (base + 3 < n) rowptr[base + 4] = o3;
    if (b == 0 && tid == 0) rowptr[0] = 0;
}

// pos[e] = rowptr[dst] + rank[e]; payload[e] = (src<<16) | fp16(w)
__global__ void pospay_k(const int* __restrict__ src, const int* __restrict__ dst,
                         const int* __restrict__ rank, const int* __restrict__ rowptr,
                         const float* __restrict__ dinv,
                         int* __restrict__ pos, unsigned int* __restrict__ payload, int E) {
    int e4 = blockIdx.x * 256 + threadIdx.x;
    int nE4 = E >> 2;
    if (e4 < nE4) {
        int4 d = ((const int4*)dst)[e4];
        int4 s = ((const int4*)src)[e4];
        int4 r = ((const int4*)rank)[e4];
        int ds[4] = {d.x, d.y, d.z, d.w};
        int ss[4] = {s.x, s.y, s.z, s.w};
        int rs[4] = {r.x, r.y, r.z, r.w};
        int4 po;
        uint4 py;
        int* pop = &po.x;
        unsigned int* pyp = &py.x;
#pragma unroll
        for (int j = 0; j < 4; ++j) {
            pop[j] = rowptr[ds[j]] + rs[j];
            float w = dinv[ss[j]] * dinv[ds[j]];
            unsigned short wh = __half_as_ushort(__float2half(w));
            pyp[j] = ((unsigned int)ss[j] << 16) | (unsigned int)wh;
        }
        ((int4*)pos)[e4] = po;
        ((uint4*)payload)[e4] = py;
    } else if (e4 == nE4) {
        for (int e = nE4 * 4; e < E; ++e) {
            int d = dst[e], s = src[e];
            pos[e] = rowptr[d] + rank[e];
            float w = dinv[s] * dinv[d];
            unsigned short wh = __half_as_ushort(__float2half(w));
            payload[e] = ((unsigned int)s << 16) | (unsigned int)wh;
        }
    }
}

// XCD-striped scatter: block b handles edata stripe (b&7), edge chunk (b>>3).
__global__ void scatter8_k(const int* __restrict__ pos, const unsigned int* __restrict__ payload,
                           unsigned int* __restrict__ edata, int E, int S) {
    int stripe = blockIdx.x & 7;
    int lo = stripe * S;
    int hi = min(E, lo + S);
    int e4 = (blockIdx.x >> 3) * 256 + threadIdx.x;
    int nE4 = E >> 2;
    if (e4 < nE4) {
        int4 p = ((const int4*)pos)[e4];
        uint4 y = ((const uint4*)payload)[e4];
        if (p.x >= lo && p.x < hi) edata[p.x] = y.x;
        if (p.y >= lo && p.y < hi) edata[p.y] = y.y;
        if (p.z >= lo && p.z < hi) edata[p.z] = y.z;
        if (p.w >= lo && p.w < hi) edata[p.w] = y.w;
    } else if (e4 == nE4) {
        for (int e = nE4 * 4; e < E; ++e) {
            int p = pos[e];
            if (p >= lo && p < hi) edata[p] = payload[e];
        }
    }
}

// Pre-shuffle all 4 W matrices (fp32 [128][128]) into MFMA fragment order, fp16.
// Fragment (ks, ct, lane) holds W[k][col], k = ks*32 + (lane>>4)*8 + j, col = ct*16 + (lane&15).
__global__ void wshuf_k(const float* __restrict__ W0, const float* __restrict__ W1,
                        const float* __restrict__ W2, const float* __restrict__ W3,
                        uint4* __restrict__ Wshuf) {
    int gid = blockIdx.x * 256 + threadIdx.x;  // [0, 8192)
    int layer = gid >> 11;
    int tid2 = gid & 2047;
    int ks = tid2 >> 9;
    int rem = tid2 & 511;
    int ct = rem >> 6;
    int lane = rem & 63;
    const float* W = (layer == 0) ? W0 : (layer == 1) ? W1 : (layer == 2) ? W2 : W3;
    int col = ct * 16 + (lane & 15);
    int k0 = ks * 32 + (lane >> 4) * 8;
    __half h[8];
#pragma unroll
    for (int j = 0; j < 8; ++j) h[j] = __float2half(W[(k0 + j) * 128 + col]);
    uint4 o;
    o.x = *(unsigned int*)&h[0];
    o.y = *(unsigned int*)&h[2];
    o.z = *(unsigned int*)&h[4];
    o.w = *(unsigned int*)&h[6];
    Wshuf[gid] = o;
}

// ---------------- per-layer kernels ----------------

// H = X @ W via v_mfma_f32_16x16x32_f16 with SWAPPED operands:
// D = mfma(A=w_frag, B=x_frag) = W^T · X^T, so D col (lane&15) = node and
// D rows ((lane>>4)*4+r) = 4 CONSECUTIVE H-columns -> uint2 packed store.
// 4 waves; wave = 64 nodes; block = 256 nodes.
template <bool F32IN>
__global__ __launch_bounds__(256) void gemm_k(const void* __restrict__ Xin,
                                              const uint4* __restrict__ Wsh,
                                              __half* __restrict__ Hh, int N) {
    __shared__ uint4 bsh[2048];  // 32 KB
    int tid = threadIdx.x;
#pragma unroll
    for (int i = 0; i < 8; ++i) bsh[i * 256 + tid] = Wsh[i * 256 + tid];
    __syncthreads();

    int lane = tid & 63;
    int wv = tid >> 6;
    int rbase = blockIdx.x * 256 + wv * 64;
    int lr = lane & 15;
    int lk = lane >> 4;

    f32x4 acc[4][8];
#pragma unroll
    for (int rt = 0; rt < 4; ++rt)
#pragma unroll
        for (int ct = 0; ct < 8; ++ct) acc[rt][ct] = (f32x4){0.f, 0.f, 0.f, 0.f};

#pragma unroll
    for (int ks = 0; ks < 4; ++ks) {
        half8 a[4];
#pragma unroll
        for (int rt = 0; rt < 4; ++rt) {
            int row = rbase + rt * 16 + lr;
            if (F32IN) {
                half8 h = (half8)(_Float16)0;
                if (row < N) {
                    const float4* xf = (const float4*)((const float*)Xin +
                                        (size_t)row * 128 + (ks * 4 + lk) * 8);
                    float4 f0 = xf[0];
                    float4 f1 = xf[1];
                    h[0] = (_Float16)f0.x; h[1] = (_Float16)f0.y;
                    h[2] = (_Float16)f0.z; h[3] = (_Float16)f0.w;
                    h[4] = (_Float16)f1.x; h[5] = (_Float16)f1.y;
                    h[6] = (_Float16)f1.z; h[7] = (_Float16)f1.w;
                }
                a[rt] = h;
            } else {
                uint4 u = (row < N) ? ((const uint4*)Xin)[(size_t)row * 16 + ks * 4 + lk]
                                    : make_uint4(0, 0, 0, 0);
                a[rt] = as_half8(u);
            }
        }
#pragma unroll
        for (int ct = 0; ct < 8; ++ct) {
            half8 b = as_half8(bsh[(ks * 8 + ct) * 64 + lane]);
#pragma unroll
            for (int rt = 0; rt < 4; ++rt) {
                // swapped: D = W^T · X^T  (node in D-col, H-cols in D-rows)
                acc[rt][ct] = __builtin_amdgcn_mfma_f32_16x16x32_f16(b, a[rt], acc[rt][ct], 0, 0, 0);
            }
        }
    }

    // lane holds node = rbase + rt*16 + lr ; H cols = ct*16 + lk*4 + {0..3}
#pragma unroll
    for (int rt = 0; rt < 4; ++rt) {
        int node = rbase + rt * 16 + lr;
        if (node < N) {
#pragma unroll
            for (int ct = 0; ct < 8; ++ct) {
                f32x4 v = acc[rt][ct];
                __half2 h0 = __floats2half2_rn(v[0], v[1]);
                __half2 h1 = __floats2half2_rn(v[2], v[3]);
                uint2 o;
                o.x = *(unsigned int*)&h0;
                o.y = *(unsigned int*)&h1;
                *(uint2*)(Hh + (size_t)node * 128 + ct * 16 + lk * 4) = o;
            }
        }
    }
}

__device__ __forceinline__ void acc4(float* a, uint2 v, float w) {
    __half2 h0 = *(__half2*)&v.x;
    __half2 h1 = *(__half2*)&v.y;
    float2 f0 = __half22float2(h0);
    float2 f1 = __half22float2(h1);
    a[0] = fmaf(f0.x, w, a[0]);
    a[1] = fmaf(f0.y, w, a[1]);
    a[2] = fmaf(f1.x, w, a[2]);
    a[3] = fmaf(f1.y, w, a[3]);
}

// out[i] = relu(b + dinv[i]^2 * H[i] + sum_{e: dst=i} w_e * H[src_e])
// XCD-pinned feature chunks: chunk = bid&1 (128B half-row); with round-robin
// bid->XCD dispatch, each XCD only ever touches one 6.4MB half of H.
// 16 lanes/node x uint2 (8B).
template <bool F16OUT>
__global__ __launch_bounds__(256) void gather_agg_k(
        const __half* __restrict__ Hh, const int* __restrict__ rowptr,
        const unsigned int* __restrict__ edata, const float* __restrict__ dinv,
        const float* __restrict__ b, void* __restrict__ out, int N) {
    int bid = blockIdx.x;
    int c = bid & 1;
    int g = bid >> 1;
    int t = g * 256 + threadIdx.x;
    int i = t >> 4;
    if (i >= N) return;
    int lane = t & 15;
    int fo = c * 16 + lane;              // uint2 index within 32-uint2 row
    const uint2* H2 = (const uint2*)Hh;

    float dn = dinv[i];
    float sn = dn * dn;

    float a[4] = {};
    acc4(a, H2[(size_t)i * 32 + fo], sn);

    int p0 = rowptr[i];
    int p1 = rowptr[i + 1];
    int p = p0;
    for (; p + 8 <= p1; p += 8) {
        unsigned int e0 = edata[p + 0];
        unsigned int e1 = edata[p + 1];
        unsigned int e2 = edata[p + 2];
        unsigned int e3 = edata[p + 3];
        unsigned int e4 = edata[p + 4];
        unsigned int e5 = edata[p + 5];
        unsigned int e6 = edata[p + 6];
        unsigned int e7 = edata[p + 7];
        uint2 v0 = H2[(size_t)(e0 >> 16) * 32 + fo];
        uint2 v1 = H2[(size_t)(e1 >> 16) * 32 + fo];
        uint2 v2 = H2[(size_t)(e2 >> 16) * 32 + fo];
        uint2 v3 = H2[(size_t)(e3 >> 16) * 32 + fo];
        uint2 v4 = H2[(size_t)(e4 >> 16) * 32 + fo];
        uint2 v5 = H2[(size_t)(e5 >> 16) * 32 + fo];
        uint2 v6 = H2[(size_t)(e6 >> 16) * 32 + fo];
        uint2 v7 = H2[(size_t)(e7 >> 16) * 32 + fo];
        acc4(a, v0, __half2float(__ushort_as_half((unsigned short)(e0 & 0xffffu))));
        acc4(a, v1, __half2float(__ushort_as_half((unsigned short)(e1 & 0xffffu))));
        acc4(a, v2, __half2float(__ushort_as_half((unsigned short)(e2 & 0xffffu))));
        acc4(a, v3, __half2float(__ushort_as_half((unsigned short)(e3 & 0xffffu))));
        acc4(a, v4, __half2float(__ushort_as_half((unsigned short)(e4 & 0xffffu))));
        acc4(a, v5, __half2float(__ushort_as_half((unsigned short)(e5 & 0xffffu))));
        acc4(a, v6, __half2float(__ushort_as_half((unsigned short)(e6 & 0xffffu))));
        acc4(a, v7, __half2float(__ushort_as_half((unsigned short)(e7 & 0xffffu))));
    }
    for (; p + 4 <= p1; p += 4) {
        unsigned int e0 = edata[p + 0];
        unsigned int e1 = edata[p + 1];
        unsigned int e2 = edata[p + 2];
        unsigned int e3 = edata[p + 3];
        uint2 v0 = H2[(size_t)(e0 >> 16) * 32 + fo];
        uint2 v1 = H2[(size_t)(e1 >> 16) * 32 + fo];
        uint2 v2 = H2[(size_t)(e2 >> 16) * 32 + fo];
        uint2 v3 = H2[(size_t)(e3 >> 16) * 32 + fo];
        acc4(a, v0, __half2float(__ushort_as_half((unsigned short)(e0 & 0xffffu))));
        acc4(a, v1, __half2float(__ushort_as_half((unsigned short)(e1 & 0xffffu))));
        acc4(a, v2, __half2float(__ushort_as_half((unsigned short)(e2 & 0xffffu))));
        acc4(a, v3, __half2float(__ushort_as_half((unsigned short)(e3 & 0xffffu))));
    }
    for (; p < p1; ++p) {
        unsigned int e = edata[p];
        uint2 v = H2[(size_t)(e >> 16) * 32 + fo];
        acc4(a, v, __half2float(__ushort_as_half((unsigned short)(e & 0xffffu))));
    }

    float4 bb = ((const float4*)b)[fo];
    float r0 = fmaxf(a[0] + bb.x, 0.f);
    float r1 = fmaxf(a[1] + bb.y, 0.f);
    float r2 = fmaxf(a[2] + bb.z, 0.f);
    float r3 = fmaxf(a[3] + bb.w, 0.f);

    if (F16OUT) {
        __half2 h0 = __floats2half2_rn(r0, r1);
        __half2 h1 = __floats2half2_rn(r2, r3);
        uint2 o;
        o.x = *(unsigned int*)&h0;
        o.y = *(unsigned int*)&h1;
        ((uint2*)out)[(size_t)i * 32 + fo] = o;
    } else {
        *(float4*)((float*)out + (size_t)i * 128 + fo * 4) = make_float4(r0, r1, r2, r3);
    }
}

// ---------------- launch ----------------

extern "C" void kernel_launch(void* const* d_in, const int* in_sizes, int n_in,
                              void* d_out, int out_size, void* d_ws, size_t ws_size,
                              hipStream_t stream) {
    const float* x = (const float*)d_in[0];
    const int* ei = (const int*)d_in[1];
    const int E = in_sizes[1] / 2;
    const int* srcI = ei;
    const int* dstI = ei + E;
    const float* b[4] = {(const float*)d_in[3], (const float*)d_in[5],
                         (const float*)d_in[7], (const float*)d_in[9]};
    const int N = in_sizes[0] / 128;
    const int Ea = (E + 3) & ~3;

    // ws layout (4B units)
    int* iws = (int*)d_ws;
    int* cnt = iws;                              // [0, 50176)
    int* rowptr = iws + 50176;                   // [50176, 100352)
    float* dinv = (float*)(iws + 100352);        // [100352, 150528)
    int* bsum = iws + 150528;                    // 64
    int* rank = iws + 150656;                    // Ea
    int* pos = rank + Ea;                        // Ea
    unsigned int* payload = (unsigned int*)(pos + Ea);      // Ea
    unsigned int* edata = payload + Ea;          // Ea
    uint4* Wshuf = (uint4*)(edata + Ea);         // 8192 uint4
    int* wsEnd = (int*)(Wshuf + 8192);
    __half* Xh = (__half*)wsEnd;                 // N*128 halves (inter-layer act)
    __half* Hh = (__half*)(wsEnd + (size_t)N * 64);

    dim3 blk(256);
    int gE4 = ((E >> 2) + 1 + 255) / 256;
    int NB = (N + 1023) / 1024;
    int gGemm = (N + 255) / 256;
    int G = (N * 16 + 255) / 256;                // node-group count for gather
    int S = (((E + 7) / 8) + 31) & ~31;          // stripe size, 128B-aligned

    zero_k<<<49, blk, 0, stream>>>(cnt);
    hist_rank_k<<<gE4, blk, 0, stream>>>(dstI, cnt, rank, E);
    bsum_k<<<NB, blk, 0, stream>>>(cnt, bsum, dinv, N);
    rowscan_k<<<NB, blk, 0, stream>>>(cnt, bsum, rowptr, N);
    pospay_k<<<gE4, blk, 0, stream>>>(srcI, dstI, rank, rowptr, dinv, pos, payload, E);
    scatter8_k<<<gE4 * 8, blk, 0, stream>>>(pos, payload, edata, E, S);
    wshuf_k<<<32, blk, 0, stream>>>((const float*)d_in[2], (const float*)d_in[4],
                                    (const float*)d_in[6], (const float*)d_in[8], Wshuf);

    for (int l = 0; l < 4; ++l) {
        if (l == 0) gemm_k<true><<<gGemm, blk, 0, stream>>>(x, Wshuf, Hh, N);
        else        gemm_k<false><<<gGemm, blk, 0, stream>>>(Xh, Wshuf + l * 2048, Hh, N);
        if (l == 3) {
            gather_agg_k<false><<<2 * G, blk, 0, stream>>>(Hh, rowptr, edata, dinv, b[l], d_out, N);
        } else {
            gather_agg_k<true><<<2 * G, blk, 0, stream>>>(Hh, rowptr, edata, dinv, b[l], Xh, N);
        }
    }
}